// Round 1
// baseline (623.938 us; speedup 1.0000x reference)
//
#include <hip/hip_runtime.h>

#define N_NODES   100352
#define N_EDGES   1605632
#define IN_C      128
#define HID_C     64
#define OUT_C     32
#define NUM_GRAPHS 512
#define NPG       196
#define TOPK      30

// ws layout (bytes)
#define OFF_DEG     0u          // int[N]
#define OFF_ROWPTR  401408u     // int[N]
#define OFF_FILL    802816u     // int[N]
#define OFF_BSUM    1204224u    // int[98]
#define OFF_BOFF    1204736u    // int[98]
#define OFF_DIS     1205248u    // double[N]
#define OFF_CSR     2008064u    // int[E]
#define OFF_XW1     8430592u    // float[N*64]
#define OFF_H       34120704u   // float[N*64]
#define OFF_XW2     59810816u   // float[N*32]
#define OFF_OUT2    72655872u   // double[N*32]
// total: 98345984 bytes (~94 MB)

__global__ void k_deg(const int* __restrict__ dst, int* __restrict__ deg) {
    int i = blockIdx.x * blockDim.x + threadIdx.x;
    if (i < N_EDGES) atomicAdd(&deg[dst[i]], 1);
}

__global__ __launch_bounds__(1024) void k_bsum(const int* __restrict__ deg, int* __restrict__ bsum) {
    __shared__ int s[1024];
    int t = threadIdx.x;
    s[t] = deg[blockIdx.x * 1024 + t];
    __syncthreads();
    for (int o = 512; o > 0; o >>= 1) {
        if (t < o) s[t] += s[t + o];
        __syncthreads();
    }
    if (t == 0) bsum[blockIdx.x] = s[0];
}

__global__ void k_bscan(const int* __restrict__ bsum, int* __restrict__ boff) {
    if (threadIdx.x == 0) {
        int run = 0;
        for (int b = 0; b < 98; ++b) { boff[b] = run; run += bsum[b]; }
    }
}

__global__ __launch_bounds__(1024) void k_scan(const int* __restrict__ deg, const int* __restrict__ boff,
                                               int* __restrict__ row_ptr, int* __restrict__ fill_pos,
                                               double* __restrict__ dis) {
    __shared__ int s[1024];
    int t = threadIdx.x;
    int i = blockIdx.x * 1024 + t;
    int v = deg[i];
    s[t] = v;
    __syncthreads();
    for (int o = 1; o < 1024; o <<= 1) {
        int a = (t >= o) ? s[t - o] : 0;
        __syncthreads();
        s[t] += a;
        __syncthreads();
    }
    int start = boff[blockIdx.x] + s[t] - v;   // exclusive prefix
    row_ptr[i] = start;
    fill_pos[i] = start;
    dis[i] = 1.0 / sqrt((double)(v + 1));       // +1 self-loop
}

__global__ void k_fill(const int* __restrict__ src, const int* __restrict__ dst,
                       int* __restrict__ fill_pos, int* __restrict__ csr_src) {
    int i = blockIdx.x * blockDim.x + threadIdx.x;
    if (i < N_EDGES) {
        int d = dst[i];
        int p = atomicAdd(&fill_pos[d], 1);
        csr_src[p] = src[i];
    }
}

// xw1 = x @ W1  (f64 accumulate, f32 store). thread = (node, col), 64 cols.
__global__ __launch_bounds__(256) void k_mm1(const float* __restrict__ x, const float* __restrict__ W1,
                                             float* __restrict__ xw1) {
    int gid = blockIdx.x * 256 + threadIdx.x;      // == node*64 + c
    int node = gid >> 6;
    int c = gid & 63;
    const float* xr = x + node * IN_C;
    double acc = 0.0;
#pragma unroll 8
    for (int k = 0; k < IN_C; ++k)
        acc += (double)xr[k] * (double)W1[k * HID_C + c];
    xw1[gid] = (float)acc;
}

// layer-1 aggregation: one 64-lane wave per node, lane = channel.
__global__ __launch_bounds__(256) void k_agg1(const float* __restrict__ xw1, const int* __restrict__ csr_src,
                                              const int* __restrict__ row_ptr, const int* __restrict__ deg,
                                              const double* __restrict__ dis, const float* __restrict__ b1,
                                              float* __restrict__ h) {
    int lane = threadIdx.x & 63;
    int v = blockIdx.x * 4 + (threadIdx.x >> 6);
    int start = row_ptr[v];
    int cnt = deg[v];
    double dv = dis[v];
    double acc = 0.0;
    for (int base = 0; base < cnt; base += 64) {
        int mcnt = min(64, cnt - base);
        int sj = 0; double dj = 0.0;
        if (lane < mcnt) { sj = csr_src[start + base + lane]; dj = dis[sj]; }
        for (int j = 0; j < mcnt; ++j) {
            int s = __shfl(sj, j);
            double ds = __shfl(dj, j);
            acc += ds * (double)xw1[s * HID_C + lane];
        }
    }
    double self = (double)xw1[v * HID_C + lane];
    double o = dv * acc + dv * dv * self + (double)b1[lane];
    h[v * HID_C + lane] = (float)fmax(o, 0.0);   // ReLU fused
}

// xw2 = h @ W2. thread = (node, col), 32 cols.
__global__ __launch_bounds__(256) void k_mm2(const float* __restrict__ h, const float* __restrict__ W2,
                                             float* __restrict__ xw2) {
    int gid = blockIdx.x * 256 + threadIdx.x;      // == node*32 + c
    int node = gid >> 5;
    int c = gid & 31;
    const float* hr = h + node * HID_C;
    double acc = 0.0;
#pragma unroll 8
    for (int k = 0; k < HID_C; ++k)
        acc += (double)hr[k] * (double)W2[k * OUT_C + c];
    xw2[gid] = (float)acc;
}

// layer-2 aggregation: 32-lane group per node; out2 stored f64 (sort-key precision).
__global__ __launch_bounds__(256) void k_agg2(const float* __restrict__ xw2, const int* __restrict__ csr_src,
                                              const int* __restrict__ row_ptr, const int* __restrict__ deg,
                                              const double* __restrict__ dis, const float* __restrict__ b2,
                                              double* __restrict__ out2) {
    int lane = threadIdx.x & 31;
    int v = blockIdx.x * 8 + (threadIdx.x >> 5);
    int start = row_ptr[v];
    int cnt = deg[v];
    double dv = dis[v];
    double acc = 0.0;
    for (int base = 0; base < cnt; base += 32) {
        int mcnt = min(32, cnt - base);
        int sj = 0; double dj = 0.0;
        if (lane < mcnt) { sj = csr_src[start + base + lane]; dj = dis[sj]; }
        for (int j = 0; j < mcnt; ++j) {
            int s = __shfl(sj, j, 32);
            double ds = __shfl(dj, j, 32);
            acc += ds * (double)xw2[s * OUT_C + lane];
        }
    }
    double self = (double)xw2[v * OUT_C + lane];
    out2[v * OUT_C + lane] = dv * acc + dv * dv * self + (double)b2[lane];
}

// per-graph top-30 by channel 31 (desc, stable), emit [512, 30*32] f32.
__global__ __launch_bounds__(256) void k_sort(const double* __restrict__ out2, float* __restrict__ out) {
    __shared__ double keys[NPG];
    __shared__ int order[TOPK];
    int g = blockIdx.x;
    int tid = threadIdx.x;
    int base = g * NPG;
    if (tid < NPG) keys[tid] = out2[(base + tid) * OUT_C + (OUT_C - 1)];
    __syncthreads();
    if (tid < NPG) {
        double my = keys[tid];
        int r = 0;
        for (int j = 0; j < NPG; ++j) {
            double kj = keys[j];
            r += (kj > my) || (kj == my && j < tid);
        }
        if (r < TOPK) order[r] = tid;
    }
    __syncthreads();
    for (int idx = tid; idx < TOPK * OUT_C; idx += 256) {
        int r = idx >> 5;
        int c = idx & 31;
        int n = order[r];
        out[g * (TOPK * OUT_C) + idx] = (float)out2[(base + n) * OUT_C + c];
    }
}

extern "C" void kernel_launch(void* const* d_in, const int* in_sizes, int n_in,
                              void* d_out, int out_size, void* d_ws, size_t ws_size,
                              hipStream_t stream) {
    const float* x  = (const float*)d_in[0];
    const int*   ei = (const int*)d_in[1];
    const int*   srcp = ei;             // edge_index[0]
    const int*   dstp = ei + N_EDGES;   // edge_index[1]
    // d_in[2] (batch) unused: graphs are contiguous 196-node blocks.
    const float* W1 = (const float*)d_in[3];
    const float* b1 = (const float*)d_in[4];
    const float* W2 = (const float*)d_in[5];
    const float* b2 = (const float*)d_in[6];
    float* out = (float*)d_out;

    char* w = (char*)d_ws;
    int*    deg      = (int*)(w + OFF_DEG);
    int*    row_ptr  = (int*)(w + OFF_ROWPTR);
    int*    fill_pos = (int*)(w + OFF_FILL);
    int*    bsum     = (int*)(w + OFF_BSUM);
    int*    boff     = (int*)(w + OFF_BOFF);
    double* dis      = (double*)(w + OFF_DIS);
    int*    csr_src  = (int*)(w + OFF_CSR);
    float*  xw1      = (float*)(w + OFF_XW1);
    float*  h        = (float*)(w + OFF_H);
    float*  xw2      = (float*)(w + OFF_XW2);
    double* out2     = (double*)(w + OFF_OUT2);

    hipMemsetAsync(deg, 0, N_NODES * sizeof(int), stream);
    k_deg  <<<(N_EDGES + 255) / 256, 256, 0, stream>>>(dstp, deg);
    k_bsum <<<98, 1024, 0, stream>>>(deg, bsum);
    k_bscan<<<1, 64, 0, stream>>>(bsum, boff);
    k_scan <<<98, 1024, 0, stream>>>(deg, boff, row_ptr, fill_pos, dis);
    k_fill <<<(N_EDGES + 255) / 256, 256, 0, stream>>>(srcp, dstp, fill_pos, csr_src);
    k_mm1  <<<N_NODES * HID_C / 256, 256, 0, stream>>>(x, W1, xw1);
    k_agg1 <<<N_NODES / 4, 256, 0, stream>>>(xw1, csr_src, row_ptr, deg, dis, b1, h);
    k_mm2  <<<N_NODES * OUT_C / 256, 256, 0, stream>>>(h, W2, xw2);
    k_agg2 <<<N_NODES / 8, 256, 0, stream>>>(xw2, csr_src, row_ptr, deg, dis, b2, out2);
    k_sort <<<NUM_GRAPHS, 256, 0, stream>>>(out2, out);
}